// Round 2
// baseline (117.963 us; speedup 1.0000x reference)
//
#include <hip/hip_runtime.h>

#define S_LEN 2048
#define DMODEL 1024
#define NH 16
#define DHD 64

typedef __attribute__((ext_vector_type(8))) short bh8;
typedef __attribute__((ext_vector_type(4))) float f32x4;
typedef __attribute__((ext_vector_type(2))) unsigned int u32x2;
typedef __attribute__((ext_vector_type(4))) unsigned int u32x4;
typedef unsigned short u16;
typedef unsigned int u32;

static __device__ __forceinline__ u16 f2bf(float f) {
    unsigned u = __builtin_bit_cast(unsigned, f);
    u += 0x7fffu + ((u >> 16) & 1u);
    return (u16)(u >> 16);
}

typedef const __attribute__((address_space(1))) void* gptr_t;
typedef __attribute__((address_space(3))) void* lptr_t;

static __device__ __forceinline__ void gll16(const void* g, void* l) {
    __builtin_amdgcn_global_load_lds((gptr_t)g, (lptr_t)l, 16, 0, 0);
}

// ---------------- convert fp32 -> bf16: weights (4x1M) + sources (3x4M) --------------
// grid 8192: blocks [0,2048) weights (512 blocks each), [2048,8192) sources (2048 each).
// 256 threads x 8 elems = 2048 elems/block. Reads float4 x2, writes 16B packed bf16.
__global__ __launch_bounds__(256) void cvt_all(const float* __restrict__ WQ, const float* __restrict__ WK,
                                               const float* __restrict__ WV, const float* __restrict__ WO,
                                               const float* __restrict__ S0, const float* __restrict__ S1,
                                               const float* __restrict__ S2,
                                               u16* __restrict__ wq, u16* __restrict__ wk,
                                               u16* __restrict__ wv, u16* __restrict__ wo,
                                               u16* __restrict__ q0, u16* __restrict__ k0,
                                               u16* __restrict__ v0) {
    int bid = blockIdx.x;
    const float* s;
    u16* o;
    size_t base;
    if (bid < 2048) {
        int wi = bid >> 9;
        s = wi == 0 ? WQ : (wi == 1 ? WK : (wi == 2 ? WV : WO));
        o = wi == 0 ? wq : (wi == 1 ? wk : (wi == 2 ? wv : wo));
        base = (size_t)(bid & 511) * 2048;
    } else {
        int r = bid - 2048;
        int si = r >> 11;
        s = si == 0 ? S0 : (si == 1 ? S1 : S2);
        o = si == 0 ? q0 : (si == 1 ? k0 : v0);
        base = (size_t)(r & 2047) * 2048;
    }
    size_t i = base + (size_t)threadIdx.x * 8;
    float4 a = *(const float4*)(s + i);
    float4 b = *(const float4*)(s + i + 4);
    u32 p0 = (u32)f2bf(a.x) | ((u32)f2bf(a.y) << 16);
    u32 p1 = (u32)f2bf(a.z) | ((u32)f2bf(a.w) << 16);
    u32 p2 = (u32)f2bf(b.x) | ((u32)f2bf(b.y) << 16);
    u32 p3 = (u32)f2bf(b.z) | ((u32)f2bf(b.w) << 16);
    *(u32x4*)(o + i) = (u32x4){p0, p1, p2, p3};
}

// ---------------- GEMM body: C[M,N] = A[M,K]*B[N,K]^T + bias, 2-phase dbuf ----------------
// OBF: 0 = f32 C, 1 = bf16 C (scaled), 2 = bf16 transposed-to-VT C (V projection)
// AF32: 1 = A is fp32 in HBM, reg-staged with fused bf16 conversion; 0 = A bf16 via gll16
template <int BM, int OBF, int AF32>
static __device__ __forceinline__ void gemm_body(const void* __restrict__ Ap, const u16* __restrict__ Bm,
                                                 const float* __restrict__ bias, void* __restrict__ Cv,
                                                 int N, int K, int bi, int bj, short* Al, short* Bl,
                                                 float oscale) {
    constexpr int MI = BM / 32;
    constexpr int NC = BM / 64;
    int tid = threadIdx.x, lane = tid & 63, w = tid >> 6;
    int ln = lane & 15, hi = lane >> 4;
    int wm = w >> 1, wn = w & 1;
    f32x4 acc[MI][4];
#pragma unroll
    for (int i = 0; i < MI; i++)
#pragma unroll
        for (int j = 0; j < 4; j++) acc[i][j] = (f32x4){0.f, 0.f, 0.f, 0.f};
    int nk = K >> 5;

    float4 fa[NC][2];  // in-flight f32 A (AF32 path)
    auto loadA = [&](int kt) {
#pragma unroll
        for (int c = 0; c < NC; ++c) {
            int o = c * 4096 + tid * 16;
            int row = o >> 6, e0 = (o & 63) >> 1;
            const float* src = (const float*)Ap + (size_t)(bi * BM + row) * K + kt * 32 + e0;
            fa[c][0] = *(const float4*)src;
            fa[c][1] = *(const float4*)(src + 4);
        }
    };
    auto writeA = [&](int buf) {
#pragma unroll
        for (int c = 0; c < NC; ++c) {
            int o = c * 4096 + tid * 16;
            u32 w0 = (u32)f2bf(fa[c][0].x) | ((u32)f2bf(fa[c][0].y) << 16);
            u32 w1 = (u32)f2bf(fa[c][0].z) | ((u32)f2bf(fa[c][0].w) << 16);
            u32 w2 = (u32)f2bf(fa[c][1].x) | ((u32)f2bf(fa[c][1].y) << 16);
            u32 w3 = (u32)f2bf(fa[c][1].z) | ((u32)f2bf(fa[c][1].w) << 16);
            *(u32x4*)((char*)(Al + buf * (BM * 32)) + o) = (u32x4){w0, w1, w2, w3};
        }
    };
    auto stageA_lds = [&](int buf, int kt) {
#pragma unroll
        for (int c = 0; c < NC; ++c) {
            int o = c * 4096 + tid * 16;
            int row = o >> 6, col = (o & 63) >> 1;
            gll16((const u16*)Ap + (size_t)(bi * BM + row) * K + kt * 32 + col,
                  (char*)(Al + buf * (BM * 32)) + o);
        }
    };
    auto stageB = [&](int buf, int kt) {
#pragma unroll
        for (int c = 0; c < 2; ++c) {
            int o = c * 4096 + tid * 16;
            int row = o >> 6, col = (o & 63) >> 1;
            gll16(Bm + (size_t)(bj * 128 + row) * K + kt * 32 + col, (char*)(Bl + buf * 4096) + o);
        }
    };

    if constexpr (AF32) { loadA(0); writeA(0); } else { stageA_lds(0, 0); }
    stageB(0, 0);
    __syncthreads();
    int cur = 0;
    for (int kt = 0; kt < nk; ++kt) {
        bool pre = (kt + 1 < nk);
        if (pre) {
            if constexpr (AF32) loadA(kt + 1); else stageA_lds(cur ^ 1, kt + 1);
            stageB(cur ^ 1, kt + 1);
        }
        bh8 av[MI], bv[4];
#pragma unroll
        for (int i = 0; i < MI; i++) av[i] = *(const bh8*)&Al[cur * (BM * 32) + (wm * (BM / 2) + i * 16 + ln) * 32 + hi * 8];
#pragma unroll
        for (int j = 0; j < 4; j++) bv[j] = *(const bh8*)&Bl[cur * 4096 + (wn * 64 + j * 16 + ln) * 32 + hi * 8];
#pragma unroll
        for (int i = 0; i < MI; i++)
#pragma unroll
            for (int j = 0; j < 4; j++)
                acc[i][j] = __builtin_amdgcn_mfma_f32_16x16x32_bf16(av[i], bv[j], acc[i][j], 0, 0, 0);
        if constexpr (AF32) { if (pre) writeA(cur ^ 1); }
        __syncthreads();
        cur ^= 1;
    }
    if constexpr (OBF == 2) {
        // V projection: write C^T into VT[b,h,d,s] via LDS transpose (reuses Al+Bl = 32KB)
#pragma unroll
        for (int j = 0; j < 4; j++) {
            int col = wn * 64 + j * 16 + ln;  // local d_model col 0..127
            float bvs = bias[bj * 128 + col];
#pragma unroll
            for (int i = 0; i < MI; i++) {
                int row0 = wm * (BM / 2) + i * 16 + hi * 4;  // local s row
                u32 p01 = (u32)f2bf(acc[i][j][0] + bvs) | ((u32)f2bf(acc[i][j][1] + bvs) << 16);
                u32 p23 = (u32)f2bf(acc[i][j][2] + bvs) | ((u32)f2bf(acc[i][j][3] + bvs) << 16);
                int idx = col * 128 + (row0 ^ ((col & 7) << 3));
                *(u32x2*)&Al[idx] = (u32x2){p01, p23};
            }
        }
        __syncthreads();
        int b = bi >> 4;
        int sbase = (bi & 15) * 128;
#pragma unroll
        for (int it = 0; it < 8; ++it) {
            int idx = it * 256 + tid;
            int dcol = idx >> 4;           // 0..127
            int sl = (idx & 15) * 8;       // 0..120
            bh8 v = *(const bh8*)&Al[dcol * 128 + (sl ^ ((dcol & 7) << 3))];
            int h = bj * 2 + (dcol >> 6), d = dcol & 63;
            *(bh8*)((u16*)Cv + ((size_t)((b * 16 + h) * 64 + d)) * 2048 + sbase + sl) = v;
        }
        return;
    }
#pragma unroll
    for (int j = 0; j < 4; j++) {
        int col = bj * 128 + wn * 64 + j * 16 + ln;
        float bvs = bias[col];
#pragma unroll
        for (int i = 0; i < MI; i++) {
            int row0 = bi * BM + wm * (BM / 2) + i * 16 + hi * 4;
#pragma unroll
            for (int rr = 0; rr < 4; rr++) {
                if (OBF) {
                    float v = (acc[i][j][rr] + bvs) * oscale;  // Q-proj folds softmax scale here
                    ((u16*)Cv)[(size_t)(row0 + rr) * N + col] = f2bf(v);
                } else {
                    ((float*)Cv)[(size_t)(row0 + rr) * N + col] = acc[i][j][rr] + bvs;
                }
            }
        }
    }
}

// fused QKV projections, A pre-converted to bf16: grid 768 (XCD-swizzled); z==2 (V) writes VT
__global__ __launch_bounds__(256, 3) void gemm_qkv(const u16* __restrict__ A0, const u16* __restrict__ A1,
                                                   const u16* __restrict__ A2, const u16* __restrict__ B0,
                                                   const u16* __restrict__ B1, const u16* __restrict__ B2,
                                                   const float* __restrict__ c0, const float* __restrict__ c1,
                                                   const float* __restrict__ c2, u16* __restrict__ C0,
                                                   u16* __restrict__ C1, u16* __restrict__ VT) {
    __shared__ short SH[16384];  // 32KB: Al(16KB) + Bl(16KB); reused whole for V transpose
    short* Al = SH;
    short* Bl = SH + 8192;
    int bid = blockIdx.x;
    int swz = (bid & 7) * 96 + (bid >> 3);
    int z = swz >> 8, t = swz & 255;
    if (z == 2) {
        gemm_body<128, 2, 0>(A2, B2, c2, VT, 1024, 1024, t >> 3, t & 7, Al, Bl, 1.0f);
    } else if (z == 0) {
        gemm_body<128, 1, 0>(A0, B0, c0, C0, 1024, 1024, t >> 3, t & 7, Al, Bl, 0.18033688f);
    } else {
        gemm_body<128, 1, 0>(A1, B1, c1, C1, 1024, 1024, t >> 3, t & 7, Al, Bl, 1.0f);
    }
}

__global__ __launch_bounds__(256) void gemm_o(const u16* __restrict__ A, const u16* __restrict__ Bm,
                                              const float* __restrict__ bias, float* __restrict__ C) {
    __shared__ short Al[2 * 64 * 32];
    __shared__ short Bl[2 * 128 * 32];
    int bid = blockIdx.x;
    int swz = (bid & 7) * 64 + (bid >> 3);
    gemm_body<64, 0, 0>(A, Bm, bias, C, 1024, 1024, swz >> 3, swz & 7, Al, Bl, 1.0f);
}

// ---------------- flash attention (causal), QBLK=128 (8 waves), KVBLK=64 ----------------
// grid 512 = 32 bh x 16 qt; CU-complementary qt round-robin.
// 3-buffer K/V pipeline, 2 tiles in flight, counted s_waitcnt vmcnt(2) + raw s_barrier
// (T3/T4: prefetch loads stay in flight ACROSS the barrier; drain-0 only in epilogue).
// Fixed-base softmax: Q pre-scaled by (1/8)*log2(e) in its projection; P = exp2(s), no
// running max (shift-invariance; |s| <~ 12 so P,SumP comfortably in f32/bf16 range).
__global__ __launch_bounds__(512) void attn_fwd(const u16* __restrict__ Qp, const u16* __restrict__ Kp,
                                                const u16* __restrict__ VT, u16* __restrict__ Ctx) {
    __shared__ short Kl[3][64 * 64];
    __shared__ short Vl[3][64 * 64];
    __shared__ short Pl[8][16 * 64];
    int tid = threadIdx.x, lane = tid & 63, w = tid >> 6;  // w 0..7
    int ln = lane & 15, hi = lane >> 4;
    int bid = blockIdx.x;
    int xcd = bid & 7, j = bid >> 3;      // j 0..63
    int rnd = j >> 5, cu = j & 31;        // rnd 0..1
    int bh = xcd * 4 + rnd * 2 + (cu >> 4);  // 4 bh per XCD -> K/V stays in XCD L2
    int qtl = cu & 15;
    int qt = rnd ? (15 - qtl) : qtl;      // complementary: per-CU steps (2qt+2)+(2(15-qt)+2)=34
    int b = bh >> 4, h = bh & 15;
    short* Pw = &Pl[w][0];
    bh8 ones;
#pragma unroll
    for (int e = 0; e < 8; e++) ones[e] = (short)0x3F80;  // bf16 1.0

    auto stage_kv = [&](int buf, int kt) {
        int o = tid * 16;          // one 16B load per thread per matrix
        int r = o >> 7;
        int slot = (o >> 4) & 7;
        gll16(Kp + ((size_t)(b * S_LEN + kt * 64 + r)) * DMODEL + h * DHD + ((slot ^ (r & 7)) << 3),
              (char*)&Kl[buf][0] + o);
        gll16(VT + ((size_t)(bh * DHD + r)) * S_LEN + kt * 64 + ((slot ^ (r & 7)) << 3),
              (char*)&Vl[buf][0] + o);
    };

    int nt = 2 * qt + 2;                  // nt >= 2 always
    int qg = (qt << 7) + w * 16 + ln;
    const bh8* qrow = (const bh8*)(Qp + ((size_t)(b * S_LEN + qg)) * DMODEL + h * DHD);
    bh8 qf0 = qrow[hi], qf1 = qrow[4 + hi];
    f32x4 ctxa[4];
    f32x4 lacc = (f32x4){0.f, 0.f, 0.f, 0.f};
#pragma unroll
    for (int i = 0; i < 4; i++) ctxa[i] = (f32x4){0.f, 0.f, 0.f, 0.f};
    // prologue: 2 tiles in flight; wait for tile 0 only (leave tile 1's 2 loads in flight)
    stage_kv(0, 0);
    stage_kv(1, 1);
    asm volatile("s_waitcnt vmcnt(2)" ::: "memory");
    __builtin_amdgcn_s_barrier();
    int cur = 0;
    for (int kt = 0; kt < nt; ++kt) {
        bool pre = (kt + 2 < nt);
        if (pre) {
            int b2 = cur + 2; if (b2 >= 3) b2 -= 3;   // = buf last read at kt-1; safe after that barrier
            stage_kv(b2, kt + 2);
        }
        f32x4 sc[4];
#pragma unroll
        for (int ks = 0; ks < 4; ++ks) sc[ks] = (f32x4){0.f, 0.f, 0.f, 0.f};
        __builtin_amdgcn_s_setprio(1);
#pragma unroll
        for (int dwin = 0; dwin < 2; ++dwin) {
            bh8 qv = dwin ? qf1 : qf0;
#pragma unroll
            for (int ks = 0; ks < 4; ++ks) {
                int r = ks * 16 + ln;
                bh8 kv = *(const bh8*)&Kl[cur][r * 64 + ((dwin * 32 + hi * 8) ^ ((r & 7) << 3))];
                sc[ks] = __builtin_amdgcn_mfma_f32_16x16x32_bf16(kv, qv, sc[ks], 0, 0, 0);
            }
        }
        __builtin_amdgcn_s_setprio(0);
        if (kt >= nt - 2) {  // tiles possibly crossing the causal diagonal
#pragma unroll
            for (int ks = 0; ks < 4; ++ks)
#pragma unroll
                for (int rr = 0; rr < 4; ++rr) {
                    int kg = kt * 64 + ks * 16 + hi * 4 + rr;
                    sc[ks][rr] = (kg <= qg) ? sc[ks][rr] : -1e30f;
                }
        }
        // fixed-base softmax: P = exp2(s) directly (s already includes 1/8*log2e from Q-proj)
#pragma unroll
        for (int ks = 0; ks < 4; ++ks) {
            u32 u0 = __builtin_bit_cast(u32, __builtin_amdgcn_exp2f(sc[ks][0]));
            u32 u1 = __builtin_bit_cast(u32, __builtin_amdgcn_exp2f(sc[ks][1]));
            u32 u2 = __builtin_bit_cast(u32, __builtin_amdgcn_exp2f(sc[ks][2]));
            u32 u3 = __builtin_bit_cast(u32, __builtin_amdgcn_exp2f(sc[ks][3]));
            // truncating bf16 pack (l computed from the same truncated P)
            u32 a01 = (u0 >> 16) | (u1 & 0xffff0000u);
            u32 a23 = (u2 >> 16) | (u3 & 0xffff0000u);
            int kloc = ks * 16 + hi * 4;
            *(u32x2*)&Pw[ln * 64 + (kloc ^ ((ln & 7) << 3))] = (u32x2){a01, a23};
        }
        __builtin_amdgcn_s_setprio(1);
#pragma unroll
        for (int kw = 0; kw < 2; ++kw) {
            bh8 pf = *(const bh8*)&Pw[ln * 64 + ((kw * 32 + hi * 8) ^ ((ln & 7) << 3))];
            lacc = __builtin_amdgcn_mfma_f32_16x16x32_bf16(ones, pf, lacc, 0, 0, 0);  // l = sum_k P
#pragma unroll
            for (int ds = 0; ds < 4; ++ds) {
                int d = ds * 16 + ln;
                bh8 vf = *(const bh8*)&Vl[cur][d * 64 + ((kw * 32 + hi * 8) ^ ((d & 7) << 3))];
                ctxa[ds] = __builtin_amdgcn_mfma_f32_16x16x32_bf16(vf, pf, ctxa[ds], 0, 0, 0);
            }
        }
        __builtin_amdgcn_s_setprio(0);
        if (kt + 1 < nt) {
            // need stage(kt+1) complete in all waves; keep stage(kt+2)'s 2 loads in flight
            if (pre) asm volatile("s_waitcnt vmcnt(2)" ::: "memory");
            else     asm volatile("s_waitcnt vmcnt(0)" ::: "memory");
            __builtin_amdgcn_s_barrier();
        }
        cur = cur + 1; if (cur >= 3) cur = 0;
    }
    float inv = 1.f / lacc[0];  // all rows of ones-MFMA output equal sum_k P[q=ln][k]
    u16* cp = Ctx + ((size_t)(b * S_LEN + qg)) * DMODEL + h * DHD;
#pragma unroll
    for (int ds = 0; ds < 4; ++ds) {
        ushort4 st;
        st.x = f2bf(ctxa[ds][0] * inv);
        st.y = f2bf(ctxa[ds][1] * inv);
        st.z = f2bf(ctxa[ds][2] * inv);
        st.w = f2bf(ctxa[ds][3] * inv);
        *(ushort4*)(cp + ds * 16 + hi * 4) = st;
    }
}

// ---------------- residual + LayerNorm ----------------
__global__ __launch_bounds__(256) void ln_res(const float* __restrict__ Xres, const float* __restrict__ Y,
                                              const float* __restrict__ gamma, const float* __restrict__ beta,
                                              float* __restrict__ out) {
    int row = blockIdx.x, tid = threadIdx.x;
    const float4* xr = (const float4*)(Xres + (size_t)row * DMODEL);
    const float4* yr = (const float4*)(Y + (size_t)row * DMODEL);
    float4 a = xr[tid], bq = yr[tid];
    float x0 = a.x + bq.x, x1 = a.y + bq.y, x2 = a.z + bq.z, x3 = a.w + bq.w;
    float s1 = x0 + x1 + x2 + x3;
    float s2 = x0 * x0 + x1 * x1 + x2 * x2 + x3 * x3;
#pragma unroll
    for (int off = 32; off > 0; off >>= 1) {
        s1 += __shfl_xor(s1, off);
        s2 += __shfl_xor(s2, off);
    }
    __shared__ float r1[4], r2[4];
    int wv = tid >> 6;
    if ((tid & 63) == 0) { r1[wv] = s1; r2[wv] = s2; }
    __syncthreads();
    s1 = r1[0] + r1[1] + r1[2] + r1[3];
    s2 = r2[0] + r2[1] + r2[2] + r2[3];
    float mu = s1 * (1.0f / 1024.0f);
    float var = s2 * (1.0f / 1024.0f) - mu * mu;
    float rstd = rsqrtf(var + 1e-5f);
    const float4* g4 = (const float4*)gamma;
    const float4* b4 = (const float4*)beta;
    float4 g = g4[tid], bb = b4[tid];
    float4 res;
    res.x = (x0 - mu) * rstd * g.x + bb.x;
    res.y = (x1 - mu) * rstd * g.y + bb.y;
    res.z = (x2 - mu) * rstd * g.z + bb.z;
    res.w = (x3 - mu) * rstd * g.w + bb.w;
    *((float4*)(out + (size_t)row * DMODEL) + tid) = res;
}

extern "C" void kernel_launch(void* const* d_in, const int* in_sizes, int n_in,
                              void* d_out, int out_size, void* d_ws, size_t ws_size,
                              hipStream_t stream) {
    const float* Qs = (const float*)d_in[0];
    const float* Ks = (const float*)d_in[1];
    const float* Vs = (const float*)d_in[2];
    const float* WQ = (const float*)d_in[5];
    const float* bQ = (const float*)d_in[6];
    const float* WK = (const float*)d_in[7];
    const float* bK = (const float*)d_in[8];
    const float* WV = (const float*)d_in[9];
    const float* bV = (const float*)d_in[10];
    const float* WO = (const float*)d_in[11];
    const float* bO = (const float*)d_in[12];
    const float* gamma = (const float*)d_in[13];
    const float* beta = (const float*)d_in[14];

    const size_t MB = 1u << 20;
    char* w8 = (char*)d_ws;
    u16* Qb  = (u16*)(w8 + 0 * MB);   // bf16 sources (8MB each)
    u16* Kb  = (u16*)(w8 + 8 * MB);
    u16* Vb  = (u16*)(w8 + 16 * MB);
    u16* WQb = (u16*)(w8 + 24 * MB);
    u16* WKb = (u16*)(w8 + 26 * MB);
    u16* WVb = (u16*)(w8 + 28 * MB);
    u16* WOb = (u16*)(w8 + 30 * MB);
    u16* Qp  = (u16*)(w8 + 32 * MB);
    u16* Kp  = (u16*)(w8 + 40 * MB);
    u16* VTb = (u16*)(w8 + 56 * MB);
    u16* Ctx = (u16*)(w8 + 64 * MB);
    float* Y2 = (float*)(w8 + 72 * MB);

    cvt_all<<<8192, 256, 0, stream>>>(WQ, WK, WV, WO, Qs, Ks, Vs, WQb, WKb, WVb, WOb, Qb, Kb, Vb);
    gemm_qkv<<<768, 256, 0, stream>>>(Qb, Kb, Vb, WQb, WKb, WVb, bQ, bK, bV, Qp, Kp, VTb);
    attn_fwd<<<512, 512, 0, stream>>>(Qp, Kp, VTb, Ctx);
    gemm_o<<<512, 256, 0, stream>>>(Ctx, WOb, bO, Y2);
    ln_res<<<4096, 256, 0, stream>>>(Qs, Y2, gamma, beta, (float*)d_out);
}

// Round 3
// 116.239 us; speedup vs baseline: 1.0148x; 1.0148x over previous
//
#include <hip/hip_runtime.h>

#define S_LEN 2048
#define DMODEL 1024
#define NH 16
#define DHD 64

typedef __attribute__((ext_vector_type(8))) short bh8;
typedef __attribute__((ext_vector_type(4))) float f32x4;
typedef __attribute__((ext_vector_type(2))) unsigned int u32x2;
typedef __attribute__((ext_vector_type(4))) unsigned int u32x4;
typedef unsigned short u16;
typedef unsigned int u32;

static __device__ __forceinline__ u16 f2bf(float f) {
    unsigned u = __builtin_bit_cast(unsigned, f);
    u += 0x7fffu + ((u >> 16) & 1u);
    return (u16)(u >> 16);
}

typedef const __attribute__((address_space(1))) void* gptr_t;
typedef __attribute__((address_space(3))) void* lptr_t;

static __device__ __forceinline__ void gll16(const void* g, void* l) {
    __builtin_amdgcn_global_load_lds((gptr_t)g, (lptr_t)l, 16, 0, 0);
}

// ---------------- convert fp32 -> bf16: weights (4x1M) + sources (3x4M) --------------
__global__ __launch_bounds__(256) void cvt_all(const float* __restrict__ WQ, const float* __restrict__ WK,
                                               const float* __restrict__ WV, const float* __restrict__ WO,
                                               const float* __restrict__ S0, const float* __restrict__ S1,
                                               const float* __restrict__ S2,
                                               u16* __restrict__ wq, u16* __restrict__ wk,
                                               u16* __restrict__ wv, u16* __restrict__ wo,
                                               u16* __restrict__ q0, u16* __restrict__ k0,
                                               u16* __restrict__ v0) {
    int bid = blockIdx.x;
    const float* s;
    u16* o;
    size_t base;
    if (bid < 2048) {
        int wi = bid >> 9;
        s = wi == 0 ? WQ : (wi == 1 ? WK : (wi == 2 ? WV : WO));
        o = wi == 0 ? wq : (wi == 1 ? wk : (wi == 2 ? wv : wo));
        base = (size_t)(bid & 511) * 2048;
    } else {
        int r = bid - 2048;
        int si = r >> 11;
        s = si == 0 ? S0 : (si == 1 ? S1 : S2);
        o = si == 0 ? q0 : (si == 1 ? k0 : v0);
        base = (size_t)(r & 2047) * 2048;
    }
    size_t i = base + (size_t)threadIdx.x * 8;
    float4 a = *(const float4*)(s + i);
    float4 b = *(const float4*)(s + i + 4);
    u32 p0 = (u32)f2bf(a.x) | ((u32)f2bf(a.y) << 16);
    u32 p1 = (u32)f2bf(a.z) | ((u32)f2bf(a.w) << 16);
    u32 p2 = (u32)f2bf(b.x) | ((u32)f2bf(b.y) << 16);
    u32 p3 = (u32)f2bf(b.z) | ((u32)f2bf(b.w) << 16);
    *(u32x4*)(o + i) = (u32x4){p0, p1, p2, p3};
}

// ---------------- GEMM body: C[M,N] = A[M,K]*B[N,K]^T + bias, 2-phase dbuf ----------------
template <int BM, int OBF, int AF32>
static __device__ __forceinline__ void gemm_body(const void* __restrict__ Ap, const u16* __restrict__ Bm,
                                                 const float* __restrict__ bias, void* __restrict__ Cv,
                                                 int N, int K, int bi, int bj, short* Al, short* Bl,
                                                 float oscale) {
    constexpr int MI = BM / 32;
    constexpr int NC = BM / 64;
    int tid = threadIdx.x, lane = tid & 63, w = tid >> 6;
    int ln = lane & 15, hi = lane >> 4;
    int wm = w >> 1, wn = w & 1;
    f32x4 acc[MI][4];
#pragma unroll
    for (int i = 0; i < MI; i++)
#pragma unroll
        for (int j = 0; j < 4; j++) acc[i][j] = (f32x4){0.f, 0.f, 0.f, 0.f};
    int nk = K >> 5;

    float4 fa[NC][2];  // in-flight f32 A (AF32 path)
    auto loadA = [&](int kt) {
#pragma unroll
        for (int c = 0; c < NC; ++c) {
            int o = c * 4096 + tid * 16;
            int row = o >> 6, e0 = (o & 63) >> 1;
            const float* src = (const float*)Ap + (size_t)(bi * BM + row) * K + kt * 32 + e0;
            fa[c][0] = *(const float4*)src;
            fa[c][1] = *(const float4*)(src + 4);
        }
    };
    auto writeA = [&](int buf) {
#pragma unroll
        for (int c = 0; c < NC; ++c) {
            int o = c * 4096 + tid * 16;
            u32 w0 = (u32)f2bf(fa[c][0].x) | ((u32)f2bf(fa[c][0].y) << 16);
            u32 w1 = (u32)f2bf(fa[c][0].z) | ((u32)f2bf(fa[c][0].w) << 16);
            u32 w2 = (u32)f2bf(fa[c][1].x) | ((u32)f2bf(fa[c][1].y) << 16);
            u32 w3 = (u32)f2bf(fa[c][1].z) | ((u32)f2bf(fa[c][1].w) << 16);
            *(u32x4*)((char*)(Al + buf * (BM * 32)) + o) = (u32x4){w0, w1, w2, w3};
        }
    };
    auto stageA_lds = [&](int buf, int kt) {
#pragma unroll
        for (int c = 0; c < NC; ++c) {
            int o = c * 4096 + tid * 16;
            int row = o >> 6, col = (o & 63) >> 1;
            gll16((const u16*)Ap + (size_t)(bi * BM + row) * K + kt * 32 + col,
                  (char*)(Al + buf * (BM * 32)) + o);
        }
    };
    auto stageB = [&](int buf, int kt) {
#pragma unroll
        for (int c = 0; c < 2; ++c) {
            int o = c * 4096 + tid * 16;
            int row = o >> 6, col = (o & 63) >> 1;
            gll16(Bm + (size_t)(bj * 128 + row) * K + kt * 32 + col, (char*)(Bl + buf * 4096) + o);
        }
    };

    if constexpr (AF32) { loadA(0); writeA(0); } else { stageA_lds(0, 0); }
    stageB(0, 0);
    __syncthreads();
    int cur = 0;
    for (int kt = 0; kt < nk; ++kt) {
        bool pre = (kt + 1 < nk);
        if (pre) {
            if constexpr (AF32) loadA(kt + 1); else stageA_lds(cur ^ 1, kt + 1);
            stageB(cur ^ 1, kt + 1);
        }
        bh8 av[MI], bv[4];
#pragma unroll
        for (int i = 0; i < MI; i++) av[i] = *(const bh8*)&Al[cur * (BM * 32) + (wm * (BM / 2) + i * 16 + ln) * 32 + hi * 8];
#pragma unroll
        for (int j = 0; j < 4; j++) bv[j] = *(const bh8*)&Bl[cur * 4096 + (wn * 64 + j * 16 + ln) * 32 + hi * 8];
#pragma unroll
        for (int i = 0; i < MI; i++)
#pragma unroll
            for (int j = 0; j < 4; j++)
                acc[i][j] = __builtin_amdgcn_mfma_f32_16x16x32_bf16(av[i], bv[j], acc[i][j], 0, 0, 0);
        if constexpr (AF32) { if (pre) writeA(cur ^ 1); }
        __syncthreads();
        cur ^= 1;
    }
    if constexpr (OBF == 2) {
        // V projection: write C^T into VT[b,h,d,s] via LDS transpose (reuses Al+Bl = 32KB)
#pragma unroll
        for (int j = 0; j < 4; j++) {
            int col = wn * 64 + j * 16 + ln;  // local d_model col 0..127
            float bvs = bias[bj * 128 + col];
#pragma unroll
            for (int i = 0; i < MI; i++) {
                int row0 = wm * (BM / 2) + i * 16 + hi * 4;  // local s row
                u32 p01 = (u32)f2bf(acc[i][j][0] + bvs) | ((u32)f2bf(acc[i][j][1] + bvs) << 16);
                u32 p23 = (u32)f2bf(acc[i][j][2] + bvs) | ((u32)f2bf(acc[i][j][3] + bvs) << 16);
                int idx = col * 128 + (row0 ^ ((col & 7) << 3));
                *(u32x2*)&Al[idx] = (u32x2){p01, p23};
            }
        }
        __syncthreads();
        int b = bi >> 4;
        int sbase = (bi & 15) * 128;
#pragma unroll
        for (int it = 0; it < 8; ++it) {
            int idx = it * 256 + tid;
            int dcol = idx >> 4;           // 0..127
            int sl = (idx & 15) * 8;       // 0..120
            bh8 v = *(const bh8*)&Al[dcol * 128 + (sl ^ ((dcol & 7) << 3))];
            int h = bj * 2 + (dcol >> 6), d = dcol & 63;
            *(bh8*)((u16*)Cv + ((size_t)((b * 16 + h) * 64 + d)) * 2048 + sbase + sl) = v;
        }
        return;
    }
#pragma unroll
    for (int j = 0; j < 4; j++) {
        int col = bj * 128 + wn * 64 + j * 16 + ln;
        float bvs = bias[col];
#pragma unroll
        for (int i = 0; i < MI; i++) {
            int row0 = bi * BM + wm * (BM / 2) + i * 16 + hi * 4;
#pragma unroll
            for (int rr = 0; rr < 4; rr++) {
                if (OBF) {
                    float v = (acc[i][j][rr] + bvs) * oscale;  // Q-proj folds softmax scale here
                    ((u16*)Cv)[(size_t)(row0 + rr) * N + col] = f2bf(v);
                } else {
                    ((float*)Cv)[(size_t)(row0 + rr) * N + col] = acc[i][j][rr] + bvs;
                }
            }
        }
    }
}

// fused QKV projections, A pre-converted to bf16: grid 768 (XCD-swizzled); z==2 (V) writes VT
__global__ __launch_bounds__(256, 3) void gemm_qkv(const u16* __restrict__ A0, const u16* __restrict__ A1,
                                                   const u16* __restrict__ A2, const u16* __restrict__ B0,
                                                   const u16* __restrict__ B1, const u16* __restrict__ B2,
                                                   const float* __restrict__ c0, const float* __restrict__ c1,
                                                   const float* __restrict__ c2, u16* __restrict__ C0,
                                                   u16* __restrict__ C1, u16* __restrict__ VT) {
    __shared__ short SH[16384];  // 32KB: Al(16KB) + Bl(16KB); reused whole for V transpose
    short* Al = SH;
    short* Bl = SH + 8192;
    int bid = blockIdx.x;
    int swz = (bid & 7) * 96 + (bid >> 3);
    int z = swz >> 8, t = swz & 255;
    if (z == 2) {
        gemm_body<128, 2, 0>(A2, B2, c2, VT, 1024, 1024, t >> 3, t & 7, Al, Bl, 1.0f);
    } else if (z == 0) {
        gemm_body<128, 1, 0>(A0, B0, c0, C0, 1024, 1024, t >> 3, t & 7, Al, Bl, 0.18033688f);
    } else {
        gemm_body<128, 1, 0>(A1, B1, c1, C1, 1024, 1024, t >> 3, t & 7, Al, Bl, 1.0f);
    }
}

__global__ __launch_bounds__(256) void gemm_o(const u16* __restrict__ A, const u16* __restrict__ Bm,
                                              const float* __restrict__ bias, float* __restrict__ C) {
    __shared__ short Al[2 * 64 * 32];
    __shared__ short Bl[2 * 128 * 32];
    int bid = blockIdx.x;
    int swz = (bid & 7) * 64 + (bid >> 3);
    gemm_body<64, 0, 0>(A, Bm, bias, C, 1024, 1024, swz >> 3, swz & 7, Al, Bl, 1.0f);
}

// ---------------- flash attention (causal), QBLK=64 (4 waves), KVBLK=64, 2-phase dbuf ----
// grid 1024 = 4 rounds x 256 CU-slots; 4 blocks/CU (40KB LDS each = 160KB exactly).
// 4 INDEPENDENT phase streams per CU: when one block is in softmax-VALU another is in MFMA
// (m114 cross-wave pipe overlap). Per-CU load balanced: rounds (0,1) and (2,3) are
// complementary pairs (qt=2e vs 31-2e), 66 tile-steps per CU; worst instantaneous
// concurrency is 2 long streams (vs 1 in the 8-wave version).
// Fixed-base softmax: Q pre-scaled by (1/8)*log2(e) in its projection; P = exp2(s), no
// running max (shift-invariance; |s| <~ 12 so P,SumP comfortably in f32/bf16 range).
__global__ __launch_bounds__(256) void attn_fwd(const u16* __restrict__ Qp, const u16* __restrict__ Kp,
                                                const u16* __restrict__ VT, u16* __restrict__ Ctx) {
    __shared__ short Kl[2][64 * 64];
    __shared__ short Vl[2][64 * 64];
    __shared__ short Pl[4][16 * 64];
    int tid = threadIdx.x, lane = tid & 63, w = tid >> 6;  // w 0..3
    int ln = lane & 15, hi = lane >> 4;
    int bid = blockIdx.x;
    int xcd = bid & 7, j = bid >> 3;       // j 0..127
    int rnd = j >> 5, cu = j & 31;         // rnd 0..3, cu-slot 0..31
    int bh = xcd * 4 + (cu >> 4) + ((rnd >> 1) << 1);  // 4 bh per XCD -> K/V stays in XCD L2
    int qe = cu & 15;
    int qt = (rnd & 1) ? (31 - 2 * qe) : (2 * qe);  // complementary pair per CU: (qt+1)+(32-qt)=33
    int b = bh >> 4, h = bh & 15;
    short* Pw = &Pl[w][0];
    bh8 ones;
#pragma unroll
    for (int e = 0; e < 8; e++) ones[e] = (short)0x3F80;  // bf16 1.0

    auto stage_kv = [&](int buf, int kt) {
#pragma unroll
        for (int c = 0; c < 2; ++c) {
            int o = c * 4096 + tid * 16;   // 256 threads x 2 x 16B = 8KB per matrix
            int r = o >> 7;
            int slot = (o >> 4) & 7;
            gll16(Kp + ((size_t)(b * S_LEN + kt * 64 + r)) * DMODEL + h * DHD + ((slot ^ (r & 7)) << 3),
                  (char*)&Kl[buf][0] + o);
            gll16(VT + ((size_t)(bh * DHD + r)) * S_LEN + kt * 64 + ((slot ^ (r & 7)) << 3),
                  (char*)&Vl[buf][0] + o);
        }
    };

    int nt = qt + 1;                       // causal: kv tiles 0..qt
    int qg = (qt << 6) + w * 16 + ln;
    const bh8* qrow = (const bh8*)(Qp + ((size_t)(b * S_LEN + qg)) * DMODEL + h * DHD);
    bh8 qf0 = qrow[hi], qf1 = qrow[4 + hi];
    f32x4 ctxa[4];
    f32x4 lacc = (f32x4){0.f, 0.f, 0.f, 0.f};
#pragma unroll
    for (int i = 0; i < 4; i++) ctxa[i] = (f32x4){0.f, 0.f, 0.f, 0.f};
    stage_kv(0, 0);
    __syncthreads();
    int cur = 0;
    for (int kt = 0; kt < nt; ++kt) {
        if (kt + 1 < nt) stage_kv(cur ^ 1, kt + 1);
        f32x4 sc[4];
#pragma unroll
        for (int ks = 0; ks < 4; ++ks) sc[ks] = (f32x4){0.f, 0.f, 0.f, 0.f};
        __builtin_amdgcn_s_setprio(1);
#pragma unroll
        for (int dwin = 0; dwin < 2; ++dwin) {
            bh8 qv = dwin ? qf1 : qf0;
#pragma unroll
            for (int ks = 0; ks < 4; ++ks) {
                int r = ks * 16 + ln;
                bh8 kv = *(const bh8*)&Kl[cur][r * 64 + ((dwin * 32 + hi * 8) ^ ((r & 7) << 3))];
                sc[ks] = __builtin_amdgcn_mfma_f32_16x16x32_bf16(kv, qv, sc[ks], 0, 0, 0);
            }
        }
        __builtin_amdgcn_s_setprio(0);
        if (kt == nt - 1) {  // only the last tile touches the causal diagonal (KVBLK==QBLK)
#pragma unroll
            for (int ks = 0; ks < 4; ++ks)
#pragma unroll
                for (int rr = 0; rr < 4; ++rr) {
                    int kg = kt * 64 + ks * 16 + hi * 4 + rr;
                    sc[ks][rr] = (kg <= qg) ? sc[ks][rr] : -1e30f;
                }
        }
        // fixed-base softmax: P = exp2(s) directly (s already includes 1/8*log2e from Q-proj)
#pragma unroll
        for (int ks = 0; ks < 4; ++ks) {
            u32 u0 = __builtin_bit_cast(u32, __builtin_amdgcn_exp2f(sc[ks][0]));
            u32 u1 = __builtin_bit_cast(u32, __builtin_amdgcn_exp2f(sc[ks][1]));
            u32 u2 = __builtin_bit_cast(u32, __builtin_amdgcn_exp2f(sc[ks][2]));
            u32 u3 = __builtin_bit_cast(u32, __builtin_amdgcn_exp2f(sc[ks][3]));
            // truncating bf16 pack (l computed from the same truncated P)
            u32 a01 = (u0 >> 16) | (u1 & 0xffff0000u);
            u32 a23 = (u2 >> 16) | (u3 & 0xffff0000u);
            int kloc = ks * 16 + hi * 4;
            *(u32x2*)&Pw[ln * 64 + (kloc ^ ((ln & 7) << 3))] = (u32x2){a01, a23};
        }
        __builtin_amdgcn_s_setprio(1);
#pragma unroll
        for (int kw = 0; kw < 2; ++kw) {
            bh8 pf = *(const bh8*)&Pw[ln * 64 + ((kw * 32 + hi * 8) ^ ((ln & 7) << 3))];
            lacc = __builtin_amdgcn_mfma_f32_16x16x32_bf16(ones, pf, lacc, 0, 0, 0);  // l = sum_k P
#pragma unroll
            for (int ds = 0; ds < 4; ++ds) {
                int d = ds * 16 + ln;
                bh8 vf = *(const bh8*)&Vl[cur][d * 64 + ((kw * 32 + hi * 8) ^ ((d & 7) << 3))];
                ctxa[ds] = __builtin_amdgcn_mfma_f32_16x16x32_bf16(vf, pf, ctxa[ds], 0, 0, 0);
            }
        }
        __builtin_amdgcn_s_setprio(0);
        __syncthreads();
        cur ^= 1;
    }
    float inv = 1.f / lacc[0];  // all rows of ones-MFMA output equal sum_k P[q=ln][k]
    u16* cp = Ctx + ((size_t)(b * S_LEN + qg)) * DMODEL + h * DHD;
#pragma unroll
    for (int ds = 0; ds < 4; ++ds) {
        ushort4 st;
        st.x = f2bf(ctxa[ds][0] * inv);
        st.y = f2bf(ctxa[ds][1] * inv);
        st.z = f2bf(ctxa[ds][2] * inv);
        st.w = f2bf(ctxa[ds][3] * inv);
        *(ushort4*)(cp + ds * 16 + hi * 4) = st;
    }
}

// ---------------- residual + LayerNorm ----------------
__global__ __launch_bounds__(256) void ln_res(const float* __restrict__ Xres, const float* __restrict__ Y,
                                              const float* __restrict__ gamma, const float* __restrict__ beta,
                                              float* __restrict__ out) {
    int row = blockIdx.x, tid = threadIdx.x;
    const float4* xr = (const float4*)(Xres + (size_t)row * DMODEL);
    const float4* yr = (const float4*)(Y + (size_t)row * DMODEL);
    float4 a = xr[tid], bq = yr[tid];
    float x0 = a.x + bq.x, x1 = a.y + bq.y, x2 = a.z + bq.z, x3 = a.w + bq.w;
    float s1 = x0 + x1 + x2 + x3;
    float s2 = x0 * x0 + x1 * x1 + x2 * x2 + x3 * x3;
#pragma unroll
    for (int off = 32; off > 0; off >>= 1) {
        s1 += __shfl_xor(s1, off);
        s2 += __shfl_xor(s2, off);
    }
    __shared__ float r1[4], r2[4];
    int wv = tid >> 6;
    if ((tid & 63) == 0) { r1[wv] = s1; r2[wv] = s2; }
    __syncthreads();
    s1 = r1[0] + r1[1] + r1[2] + r1[3];
    s2 = r2[0] + r2[1] + r2[2] + r2[3];
    float mu = s1 * (1.0f / 1024.0f);
    float var = s2 * (1.0f / 1024.0f) - mu * mu;
    float rstd = rsqrtf(var + 1e-5f);
    const float4* g4 = (const float4*)gamma;
    const float4* b4 = (const float4*)beta;
    float4 g = g4[tid], bb = b4[tid];
    float4 res;
    res.x = (x0 - mu) * rstd * g.x + bb.x;
    res.y = (x1 - mu) * rstd * g.y + bb.y;
    res.z = (x2 - mu) * rstd * g.z + bb.z;
    res.w = (x3 - mu) * rstd * g.w + bb.w;
    *((float4*)(out + (size_t)row * DMODEL) + tid) = res;
}

extern "C" void kernel_launch(void* const* d_in, const int* in_sizes, int n_in,
                              void* d_out, int out_size, void* d_ws, size_t ws_size,
                              hipStream_t stream) {
    const float* Qs = (const float*)d_in[0];
    const float* Ks = (const float*)d_in[1];
    const float* Vs = (const float*)d_in[2];
    const float* WQ = (const float*)d_in[5];
    const float* bQ = (const float*)d_in[6];
    const float* WK = (const float*)d_in[7];
    const float* bK = (const float*)d_in[8];
    const float* WV = (const float*)d_in[9];
    const float* bV = (const float*)d_in[10];
    const float* WO = (const float*)d_in[11];
    const float* bO = (const float*)d_in[12];
    const float* gamma = (const float*)d_in[13];
    const float* beta = (const float*)d_in[14];

    const size_t MB = 1u << 20;
    char* w8 = (char*)d_ws;
    u16* Qb  = (u16*)(w8 + 0 * MB);   // bf16 sources (8MB each)
    u16* Kb  = (u16*)(w8 + 8 * MB);
    u16* Vb  = (u16*)(w8 + 16 * MB);
    u16* WQb = (u16*)(w8 + 24 * MB);
    u16* WKb = (u16*)(w8 + 26 * MB);
    u16* WVb = (u16*)(w8 + 28 * MB);
    u16* WOb = (u16*)(w8 + 30 * MB);
    u16* Qp  = (u16*)(w8 + 32 * MB);
    u16* Kp  = (u16*)(w8 + 40 * MB);
    u16* VTb = (u16*)(w8 + 56 * MB);
    u16* Ctx = (u16*)(w8 + 64 * MB);
    float* Y2 = (float*)(w8 + 72 * MB);

    cvt_all<<<8192, 256, 0, stream>>>(WQ, WK, WV, WO, Qs, Ks, Vs, WQb, WKb, WVb, WOb, Qb, Kb, Vb);
    gemm_qkv<<<768, 256, 0, stream>>>(Qb, Kb, Vb, WQb, WKb, WVb, bQ, bK, bV, Qp, Kp, VTb);
    attn_fwd<<<1024, 256, 0, stream>>>(Qp, Kp, VTb, Ctx);
    gemm_o<<<512, 256, 0, stream>>>(Ctx, WOb, bO, Y2);
    ln_res<<<4096, 256, 0, stream>>>(Qs, Y2, gamma, beta, (float*)d_out);
}

// Round 4
// 115.800 us; speedup vs baseline: 1.0187x; 1.0038x over previous
//
#include <hip/hip_runtime.h>

#define S_LEN 2048
#define DMODEL 1024
#define NH 16
#define DHD 64

typedef __attribute__((ext_vector_type(8))) short bh8;
typedef __attribute__((ext_vector_type(4))) float f32x4;
typedef __attribute__((ext_vector_type(2))) unsigned int u32x2;
typedef __attribute__((ext_vector_type(4))) unsigned int u32x4;
typedef unsigned short u16;
typedef unsigned int u32;

static __device__ __forceinline__ u16 f2bf(float f) {
    unsigned u = __builtin_bit_cast(unsigned, f);
    u += 0x7fffu + ((u >> 16) & 1u);
    return (u16)(u >> 16);
}

typedef const __attribute__((address_space(1))) void* gptr_t;
typedef __attribute__((address_space(3))) void* lptr_t;

static __device__ __forceinline__ void gll16(const void* g, void* l) {
    __builtin_amdgcn_global_load_lds((gptr_t)g, (lptr_t)l, 16, 0, 0);
}

// ---------------- convert fp32 -> bf16: weights (4x1M) + sources (3x4M) --------------
__global__ __launch_bounds__(256) void cvt_all(const float* __restrict__ WQ, const float* __restrict__ WK,
                                               const float* __restrict__ WV, const float* __restrict__ WO,
                                               const float* __restrict__ S0, const float* __restrict__ S1,
                                               const float* __restrict__ S2,
                                               u16* __restrict__ wq, u16* __restrict__ wk,
                                               u16* __restrict__ wv, u16* __restrict__ wo,
                                               u16* __restrict__ q0, u16* __restrict__ k0,
                                               u16* __restrict__ v0) {
    int bid = blockIdx.x;
    const float* s;
    u16* o;
    size_t base;
    if (bid < 2048) {
        int wi = bid >> 9;
        s = wi == 0 ? WQ : (wi == 1 ? WK : (wi == 2 ? WV : WO));
        o = wi == 0 ? wq : (wi == 1 ? wk : (wi == 2 ? wv : wo));
        base = (size_t)(bid & 511) * 2048;
    } else {
        int r = bid - 2048;
        int si = r >> 11;
        s = si == 0 ? S0 : (si == 1 ? S1 : S2);
        o = si == 0 ? q0 : (si == 1 ? k0 : v0);
        base = (size_t)(r & 2047) * 2048;
    }
    size_t i = base + (size_t)threadIdx.x * 8;
    float4 a = *(const float4*)(s + i);
    float4 b = *(const float4*)(s + i + 4);
    u32 p0 = (u32)f2bf(a.x) | ((u32)f2bf(a.y) << 16);
    u32 p1 = (u32)f2bf(a.z) | ((u32)f2bf(a.w) << 16);
    u32 p2 = (u32)f2bf(b.x) | ((u32)f2bf(b.y) << 16);
    u32 p3 = (u32)f2bf(b.z) | ((u32)f2bf(b.w) << 16);
    *(u32x4*)(o + i) = (u32x4){p0, p1, p2, p3};
}

// ---------------- GEMM body: C[M,N] = A[M,K]*B[N,K]^T + bias, 2-phase dbuf ----------------
template <int BM, int OBF, int AF32>
static __device__ __forceinline__ void gemm_body(const void* __restrict__ Ap, const u16* __restrict__ Bm,
                                                 const float* __restrict__ bias, void* __restrict__ Cv,
                                                 int N, int K, int bi, int bj, short* Al, short* Bl,
                                                 float oscale) {
    constexpr int MI = BM / 32;
    constexpr int NC = BM / 64;
    int tid = threadIdx.x, lane = tid & 63, w = tid >> 6;
    int ln = lane & 15, hi = lane >> 4;
    int wm = w >> 1, wn = w & 1;
    f32x4 acc[MI][4];
#pragma unroll
    for (int i = 0; i < MI; i++)
#pragma unroll
        for (int j = 0; j < 4; j++) acc[i][j] = (f32x4){0.f, 0.f, 0.f, 0.f};
    int nk = K >> 5;

    float4 fa[NC][2];  // in-flight f32 A (AF32 path)
    auto loadA = [&](int kt) {
#pragma unroll
        for (int c = 0; c < NC; ++c) {
            int o = c * 4096 + tid * 16;
            int row = o >> 6, e0 = (o & 63) >> 1;
            const float* src = (const float*)Ap + (size_t)(bi * BM + row) * K + kt * 32 + e0;
            fa[c][0] = *(const float4*)src;
            fa[c][1] = *(const float4*)(src + 4);
        }
    };
    auto writeA = [&](int buf) {
#pragma unroll
        for (int c = 0; c < NC; ++c) {
            int o = c * 4096 + tid * 16;
            u32 w0 = (u32)f2bf(fa[c][0].x) | ((u32)f2bf(fa[c][0].y) << 16);
            u32 w1 = (u32)f2bf(fa[c][0].z) | ((u32)f2bf(fa[c][0].w) << 16);
            u32 w2 = (u32)f2bf(fa[c][1].x) | ((u32)f2bf(fa[c][1].y) << 16);
            u32 w3 = (u32)f2bf(fa[c][1].z) | ((u32)f2bf(fa[c][1].w) << 16);
            *(u32x4*)((char*)(Al + buf * (BM * 32)) + o) = (u32x4){w0, w1, w2, w3};
        }
    };
    auto stageA_lds = [&](int buf, int kt) {
#pragma unroll
        for (int c = 0; c < NC; ++c) {
            int o = c * 4096 + tid * 16;
            int row = o >> 6, col = (o & 63) >> 1;
            gll16((const u16*)Ap + (size_t)(bi * BM + row) * K + kt * 32 + col,
                  (char*)(Al + buf * (BM * 32)) + o);
        }
    };
    auto stageB = [&](int buf, int kt) {
#pragma unroll
        for (int c = 0; c < 2; ++c) {
            int o = c * 4096 + tid * 16;
            int row = o >> 6, col = (o & 63) >> 1;
            gll16(Bm + (size_t)(bj * 128 + row) * K + kt * 32 + col, (char*)(Bl + buf * 4096) + o);
        }
    };

    if constexpr (AF32) { loadA(0); writeA(0); } else { stageA_lds(0, 0); }
    stageB(0, 0);
    __syncthreads();
    int cur = 0;
    for (int kt = 0; kt < nk; ++kt) {
        bool pre = (kt + 1 < nk);
        if (pre) {
            if constexpr (AF32) loadA(kt + 1); else stageA_lds(cur ^ 1, kt + 1);
            stageB(cur ^ 1, kt + 1);
        }
        bh8 av[MI], bv[4];
#pragma unroll
        for (int i = 0; i < MI; i++) av[i] = *(const bh8*)&Al[cur * (BM * 32) + (wm * (BM / 2) + i * 16 + ln) * 32 + hi * 8];
#pragma unroll
        for (int j = 0; j < 4; j++) bv[j] = *(const bh8*)&Bl[cur * 4096 + (wn * 64 + j * 16 + ln) * 32 + hi * 8];
#pragma unroll
        for (int i = 0; i < MI; i++)
#pragma unroll
            for (int j = 0; j < 4; j++)
                acc[i][j] = __builtin_amdgcn_mfma_f32_16x16x32_bf16(av[i], bv[j], acc[i][j], 0, 0, 0);
        if constexpr (AF32) { if (pre) writeA(cur ^ 1); }
        __syncthreads();
        cur ^= 1;
    }
    if constexpr (OBF == 2) {
        // V projection: write C^T into VT[b,h,d,s] via LDS transpose (reuses Al+Bl = 32KB)
#pragma unroll
        for (int j = 0; j < 4; j++) {
            int col = wn * 64 + j * 16 + ln;  // local d_model col 0..127
            float bvs = bias[bj * 128 + col];
#pragma unroll
            for (int i = 0; i < MI; i++) {
                int row0 = wm * (BM / 2) + i * 16 + hi * 4;  // local s row
                u32 p01 = (u32)f2bf(acc[i][j][0] + bvs) | ((u32)f2bf(acc[i][j][1] + bvs) << 16);
                u32 p23 = (u32)f2bf(acc[i][j][2] + bvs) | ((u32)f2bf(acc[i][j][3] + bvs) << 16);
                int idx = col * 128 + (row0 ^ ((col & 7) << 3));
                *(u32x2*)&Al[idx] = (u32x2){p01, p23};
            }
        }
        __syncthreads();
        int b = bi >> 4;
        int sbase = (bi & 15) * 128;
#pragma unroll
        for (int it = 0; it < 8; ++it) {
            int idx = it * 256 + tid;
            int dcol = idx >> 4;           // 0..127
            int sl = (idx & 15) * 8;       // 0..120
            bh8 v = *(const bh8*)&Al[dcol * 128 + (sl ^ ((dcol & 7) << 3))];
            int h = bj * 2 + (dcol >> 6), d = dcol & 63;
            *(bh8*)((u16*)Cv + ((size_t)((b * 16 + h) * 64 + d)) * 2048 + sbase + sl) = v;
        }
        return;
    }
#pragma unroll
    for (int j = 0; j < 4; j++) {
        int col = bj * 128 + wn * 64 + j * 16 + ln;
        float bvs = bias[col];
#pragma unroll
        for (int i = 0; i < MI; i++) {
            int row0 = bi * BM + wm * (BM / 2) + i * 16 + hi * 4;
#pragma unroll
            for (int rr = 0; rr < 4; rr++) {
                if (OBF) {
                    float v = (acc[i][j][rr] + bvs) * oscale;  // Q-proj folds softmax scale here
                    ((u16*)Cv)[(size_t)(row0 + rr) * N + col] = f2bf(v);
                } else {
                    ((float*)Cv)[(size_t)(row0 + rr) * N + col] = acc[i][j][rr] + bvs;
                }
            }
        }
    }
}

// fused QKV projections, A pre-converted to bf16: grid 768 (XCD-swizzled); z==2 (V) writes VT
__global__ __launch_bounds__(256, 3) void gemm_qkv(const u16* __restrict__ A0, const u16* __restrict__ A1,
                                                   const u16* __restrict__ A2, const u16* __restrict__ B0,
                                                   const u16* __restrict__ B1, const u16* __restrict__ B2,
                                                   const float* __restrict__ c0, const float* __restrict__ c1,
                                                   const float* __restrict__ c2, u16* __restrict__ C0,
                                                   u16* __restrict__ C1, u16* __restrict__ VT) {
    __shared__ short SH[16384];  // 32KB: Al(16KB) + Bl(16KB); reused whole for V transpose
    short* Al = SH;
    short* Bl = SH + 8192;
    int bid = blockIdx.x;
    int swz = (bid & 7) * 96 + (bid >> 3);
    int z = swz >> 8, t = swz & 255;
    if (z == 2) {
        gemm_body<128, 2, 0>(A2, B2, c2, VT, 1024, 1024, t >> 3, t & 7, Al, Bl, 1.0f);
    } else if (z == 0) {
        gemm_body<128, 1, 0>(A0, B0, c0, C0, 1024, 1024, t >> 3, t & 7, Al, Bl, 0.18033688f);
    } else {
        gemm_body<128, 1, 0>(A1, B1, c1, C1, 1024, 1024, t >> 3, t & 7, Al, Bl, 1.0f);
    }
}

__global__ __launch_bounds__(256) void gemm_o(const u16* __restrict__ A, const u16* __restrict__ Bm,
                                              const float* __restrict__ bias, float* __restrict__ C) {
    __shared__ short Al[2 * 64 * 32];
    __shared__ short Bl[2 * 128 * 32];
    int bid = blockIdx.x;
    int swz = (bid & 7) * 64 + (bid >> 3);
    gemm_body<64, 0, 0>(A, Bm, bias, C, 1024, 1024, swz >> 3, swz & 7, Al, Bl, 1.0f);
}

// ---------------- flash attention (causal), QBLK=64 (4 waves), KVBLK=64, 2-phase dbuf ----
// grid 1024 = 4 rounds x 256 CU-slots; 4 blocks/CU (40KB LDS each).
// PRIORITY STRATIFICATION (R3 experiment): the dispatch's critical path is the longest
// causal stream (qt=31: 32 serial tiles). Long streams (qt>=16) run at wave prio 2
// (3 in MFMA bursts); short streams at 0 (1 in MFMA). Short streams have huge slack and
// should only backfill the critical waves' stall slots, removing 4-way SIMD issue
// contention from the critical chain.
// Fixed-base softmax: Q pre-scaled by (1/8)*log2(e); P = exp2(s), no running max.
template <int PLO, int PHI>
static __device__ __forceinline__ void attn_core(const u16* __restrict__ Qp, const u16* __restrict__ Kp,
                                                 const u16* __restrict__ VT, u16* __restrict__ Ctx,
                                                 short* Klb, short* Vlb, short* Pw,
                                                 int b, int h, int bh, int qt, int tid) {
    int lane = tid & 63, w = tid >> 6;
    int ln = lane & 15, hi = lane >> 4;
    __builtin_amdgcn_s_setprio(PLO);
    bh8 ones;
#pragma unroll
    for (int e = 0; e < 8; e++) ones[e] = (short)0x3F80;  // bf16 1.0

    auto stage_kv = [&](int buf, int kt) {
#pragma unroll
        for (int c = 0; c < 2; ++c) {
            int o = c * 4096 + tid * 16;   // 256 threads x 2 x 16B = 8KB per matrix
            int r = o >> 7;
            int slot = (o >> 4) & 7;
            gll16(Kp + ((size_t)(b * S_LEN + kt * 64 + r)) * DMODEL + h * DHD + ((slot ^ (r & 7)) << 3),
                  (char*)(Klb + buf * 4096) + o);
            gll16(VT + ((size_t)(bh * DHD + r)) * S_LEN + kt * 64 + ((slot ^ (r & 7)) << 3),
                  (char*)(Vlb + buf * 4096) + o);
        }
    };

    int nt = qt + 1;                       // causal: kv tiles 0..qt
    int qg = (qt << 6) + w * 16 + ln;
    const bh8* qrow = (const bh8*)(Qp + ((size_t)(b * S_LEN + qg)) * DMODEL + h * DHD);
    bh8 qf0 = qrow[hi], qf1 = qrow[4 + hi];
    f32x4 ctxa[4];
    f32x4 lacc = (f32x4){0.f, 0.f, 0.f, 0.f};
#pragma unroll
    for (int i = 0; i < 4; i++) ctxa[i] = (f32x4){0.f, 0.f, 0.f, 0.f};
    stage_kv(0, 0);
    __syncthreads();
    int cur = 0;
    for (int kt = 0; kt < nt; ++kt) {
        if (kt + 1 < nt) stage_kv(cur ^ 1, kt + 1);
        f32x4 sc[4];
#pragma unroll
        for (int ks = 0; ks < 4; ++ks) sc[ks] = (f32x4){0.f, 0.f, 0.f, 0.f};
        __builtin_amdgcn_s_setprio(PHI);
#pragma unroll
        for (int dwin = 0; dwin < 2; ++dwin) {
            bh8 qv = dwin ? qf1 : qf0;
#pragma unroll
            for (int ks = 0; ks < 4; ++ks) {
                int r = ks * 16 + ln;
                bh8 kv = *(const bh8*)&Klb[cur * 4096 + r * 64 + ((dwin * 32 + hi * 8) ^ ((r & 7) << 3))];
                sc[ks] = __builtin_amdgcn_mfma_f32_16x16x32_bf16(kv, qv, sc[ks], 0, 0, 0);
            }
        }
        __builtin_amdgcn_s_setprio(PLO);
        if (kt == nt - 1) {  // only the last tile touches the causal diagonal (KVBLK==QBLK)
#pragma unroll
            for (int ks = 0; ks < 4; ++ks)
#pragma unroll
                for (int rr = 0; rr < 4; ++rr) {
                    int kg = kt * 64 + ks * 16 + hi * 4 + rr;
                    sc[ks][rr] = (kg <= qg) ? sc[ks][rr] : -1e30f;
                }
        }
        // fixed-base softmax: P = exp2(s) directly (s already includes 1/8*log2e from Q-proj)
#pragma unroll
        for (int ks = 0; ks < 4; ++ks) {
            u32 u0 = __builtin_bit_cast(u32, __builtin_amdgcn_exp2f(sc[ks][0]));
            u32 u1 = __builtin_bit_cast(u32, __builtin_amdgcn_exp2f(sc[ks][1]));
            u32 u2 = __builtin_bit_cast(u32, __builtin_amdgcn_exp2f(sc[ks][2]));
            u32 u3 = __builtin_bit_cast(u32, __builtin_amdgcn_exp2f(sc[ks][3]));
            // truncating bf16 pack (l computed from the same truncated P)
            u32 a01 = (u0 >> 16) | (u1 & 0xffff0000u);
            u32 a23 = (u2 >> 16) | (u3 & 0xffff0000u);
            int kloc = ks * 16 + hi * 4;
            *(u32x2*)&Pw[ln * 64 + (kloc ^ ((ln & 7) << 3))] = (u32x2){a01, a23};
        }
        __builtin_amdgcn_s_setprio(PHI);
#pragma unroll
        for (int kw = 0; kw < 2; ++kw) {
            bh8 pf = *(const bh8*)&Pw[ln * 64 + ((kw * 32 + hi * 8) ^ ((ln & 7) << 3))];
            lacc = __builtin_amdgcn_mfma_f32_16x16x32_bf16(ones, pf, lacc, 0, 0, 0);  // l = sum_k P
#pragma unroll
            for (int ds = 0; ds < 4; ++ds) {
                int d = ds * 16 + ln;
                bh8 vf = *(const bh8*)&Vlb[cur * 4096 + d * 64 + ((kw * 32 + hi * 8) ^ ((d & 7) << 3))];
                ctxa[ds] = __builtin_amdgcn_mfma_f32_16x16x32_bf16(vf, pf, ctxa[ds], 0, 0, 0);
            }
        }
        __builtin_amdgcn_s_setprio(PLO);
        __syncthreads();
        cur ^= 1;
    }
    float inv = 1.f / lacc[0];  // all rows of ones-MFMA output equal sum_k P[q=ln][k]
    u16* cp = Ctx + ((size_t)(b * S_LEN + qg)) * DMODEL + h * DHD;
#pragma unroll
    for (int ds = 0; ds < 4; ++ds) {
        ushort4 st;
        st.x = f2bf(ctxa[ds][0] * inv);
        st.y = f2bf(ctxa[ds][1] * inv);
        st.z = f2bf(ctxa[ds][2] * inv);
        st.w = f2bf(ctxa[ds][3] * inv);
        *(ushort4*)(cp + ds * 16 + hi * 4) = st;
    }
    __builtin_amdgcn_s_setprio(0);
}

__global__ __launch_bounds__(256) void attn_fwd(const u16* __restrict__ Qp, const u16* __restrict__ Kp,
                                                const u16* __restrict__ VT, u16* __restrict__ Ctx) {
    __shared__ short Kl[2][64 * 64];
    __shared__ short Vl[2][64 * 64];
    __shared__ short Pl[4][16 * 64];
    int tid = threadIdx.x, w = tid >> 6;
    int bid = blockIdx.x;
    int xcd = bid & 7, j = bid >> 3;       // j 0..127
    int rnd = j >> 5, cu = j & 31;         // rnd 0..3, cu-slot 0..31
    int bh = xcd * 4 + (cu >> 4) + ((rnd >> 1) << 1);  // 4 bh per XCD -> K/V stays in XCD L2
    int qe = cu & 15;
    int qt = (rnd & 1) ? (31 - 2 * qe) : (2 * qe);  // complementary pair per CU
    int b = bh >> 4, h = bh & 15;
    if (qt >= 16)
        attn_core<2, 3>(Qp, Kp, VT, Ctx, &Kl[0][0], &Vl[0][0], &Pl[w][0], b, h, bh, qt, tid);
    else
        attn_core<0, 1>(Qp, Kp, VT, Ctx, &Kl[0][0], &Vl[0][0], &Pl[w][0], b, h, bh, qt, tid);
}

// ---------------- residual + LayerNorm ----------------
__global__ __launch_bounds__(256) void ln_res(const float* __restrict__ Xres, const float* __restrict__ Y,
                                              const float* __restrict__ gamma, const float* __restrict__ beta,
                                              float* __restrict__ out) {
    int row = blockIdx.x, tid = threadIdx.x;
    const float4* xr = (const float4*)(Xres + (size_t)row * DMODEL);
    const float4* yr = (const float4*)(Y + (size_t)row * DMODEL);
    float4 a = xr[tid], bq = yr[tid];
    float x0 = a.x + bq.x, x1 = a.y + bq.y, x2 = a.z + bq.z, x3 = a.w + bq.w;
    float s1 = x0 + x1 + x2 + x3;
    float s2 = x0 * x0 + x1 * x1 + x2 * x2 + x3 * x3;
#pragma unroll
    for (int off = 32; off > 0; off >>= 1) {
        s1 += __shfl_xor(s1, off);
        s2 += __shfl_xor(s2, off);
    }
    __shared__ float r1[4], r2[4];
    int wv = tid >> 6;
    if ((tid & 63) == 0) { r1[wv] = s1; r2[wv] = s2; }
    __syncthreads();
    s1 = r1[0] + r1[1] + r1[2] + r1[3];
    s2 = r2[0] + r2[1] + r2[2] + r2[3];
    float mu = s1 * (1.0f / 1024.0f);
    float var = s2 * (1.0f / 1024.0f) - mu * mu;
    float rstd = rsqrtf(var + 1e-5f);
    const float4* g4 = (const float4*)gamma;
    const float4* b4 = (const float4*)beta;
    float4 g = g4[tid], bb = b4[tid];
    float4 res;
    res.x = (x0 - mu) * rstd * g.x + bb.x;
    res.y = (x1 - mu) * rstd * g.y + bb.y;
    res.z = (x2 - mu) * rstd * g.z + bb.z;
    res.w = (x3 - mu) * rstd * g.w + bb.w;
    *((float4*)(out + (size_t)row * DMODEL) + tid) = res;
}

extern "C" void kernel_launch(void* const* d_in, const int* in_sizes, int n_in,
                              void* d_out, int out_size, void* d_ws, size_t ws_size,
                              hipStream_t stream) {
    const float* Qs = (const float*)d_in[0];
    const float* Ks = (const float*)d_in[1];
    const float* Vs = (const float*)d_in[2];
    const float* WQ = (const float*)d_in[5];
    const float* bQ = (const float*)d_in[6];
    const float* WK = (const float*)d_in[7];
    const float* bK = (const float*)d_in[8];
    const float* WV = (const float*)d_in[9];
    const float* bV = (const float*)d_in[10];
    const float* WO = (const float*)d_in[11];
    const float* bO = (const float*)d_in[12];
    const float* gamma = (const float*)d_in[13];
    const float* beta = (const float*)d_in[14];

    const size_t MB = 1u << 20;
    char* w8 = (char*)d_ws;
    u16* Qb  = (u16*)(w8 + 0 * MB);   // bf16 sources (8MB each)
    u16* Kb  = (u16*)(w8 + 8 * MB);
    u16* Vb  = (u16*)(w8 + 16 * MB);
    u16* WQb = (u16*)(w8 + 24 * MB);
    u16* WKb = (u16*)(w8 + 26 * MB);
    u16* WVb = (u16*)(w8 + 28 * MB);
    u16* WOb = (u16*)(w8 + 30 * MB);
    u16* Qp  = (u16*)(w8 + 32 * MB);
    u16* Kp  = (u16*)(w8 + 40 * MB);
    u16* VTb = (u16*)(w8 + 56 * MB);
    u16* Ctx = (u16*)(w8 + 64 * MB);
    float* Y2 = (float*)(w8 + 72 * MB);

    cvt_all<<<8192, 256, 0, stream>>>(WQ, WK, WV, WO, Qs, Ks, Vs, WQb, WKb, WVb, WOb, Qb, Kb, Vb);
    gemm_qkv<<<768, 256, 0, stream>>>(Qb, Kb, Vb, WQb, WKb, WVb, bQ, bK, bV, Qp, Kp, VTb);
    attn_fwd<<<1024, 256, 0, stream>>>(Qp, Kp, VTb, Ctx);
    gemm_o<<<512, 256, 0, stream>>>(Ctx, WOb, bO, Y2);
    ln_res<<<4096, 256, 0, stream>>>(Qs, Y2, gamma, beta, (float*)d_out);
}